// Round 1
// baseline (301.176 us; speedup 1.0000x reference)
//
#include <hip/hip_runtime.h>
#include <hip/hip_bf16.h>

#define S 64
#define B 32
#define HID 16
#define EMB 32
#define V 50257
#define NT 3142            // ceil(V/16) tiles of 16 cols
#define VP (NT*16)         // 50272 padded V
#define NCHUNK 8
#define TPC 393            // ceil(NT/NCHUNK)
#define M 2048             // S*B rows

using bf16x8 = __attribute__((ext_vector_type(8))) __bf16;
using f32x4  = __attribute__((ext_vector_type(4))) float;

// ---------------- K1: pre-gather embeddings: emb_ws[(s*B+b)*EMB+e] ----------------
__global__ void k_gather(const int* __restrict__ idx, const float* __restrict__ emb,
                         float* __restrict__ emb_ws) {
    int i = blockIdx.x * 256 + threadIdx.x;      // 0 .. M*EMB-1 (65536)
    if (i >= M * EMB) return;
    int m = i >> 5, e = i & 31;
    emb_ws[i] = emb[(size_t)idx[m] * EMB + e];
}

// ---------------- K2: W_ho -> bf16 (padded with 0), bias padded with -1e30 --------
__global__ void k_prep(const float* __restrict__ W_ho, const float* __restrict__ b_ho,
                       __bf16* __restrict__ Wb, float* __restrict__ bias) {
    int i = blockIdx.x * 256 + threadIdx.x;
    if (i < VP) bias[i] = (i < V) ? b_ho[i] : -1e30f;
    if (i < VP * EMB) {
        int v = i >> 5;
        Wb[i] = (v < V) ? (__bf16)W_ho[i] : (__bf16)0.f;
    }
}

// ---------------- K3: the two RNN scans (one block per direction) -----------------
// thread t: b = t>>4, j = t&15. Collects PRE-states (state before consuming word s).
__global__ void k_rnn(const float* __restrict__ emb_ws,
                      const float* __restrict__ W_lr, const float* __restrict__ b_lr,
                      const float* __restrict__ W_rl, const float* __restrict__ b_rl,
                      const float* __restrict__ h0,
                      __bf16* __restrict__ hcat) {
    __shared__ float Wsh[HID][49];    // pad 49: 17*j mod 32 distinct for all j
    __shared__ float bsh[HID];
    __shared__ float embsh[B][33];
    __shared__ float hsh[B][17];
    const int t = threadIdx.x;        // 0..511
    const int dir = blockIdx.x;       // 0 = LR, 1 = RL
    const float* Wg = dir ? W_rl : W_lr;
    const float* bg = dir ? b_rl : b_lr;
    for (int i = t; i < HID * 48; i += 512) Wsh[i / 48][i % 48] = Wg[i];
    if (t < HID) bsh[t] = bg[t];
    const int b = t >> 4, j = t & 15;
    hsh[b][j] = h0[j];
    __syncthreads();
    for (int step = 0; step < S; ++step) {
        const int s = dir ? (S - 1 - step) : step;
        for (int i = t; i < B * EMB; i += 512)
            embsh[i >> 5][i & 31] = emb_ws[(s * B + (i >> 5)) * EMB + (i & 31)];
        __syncthreads();
        // store pre-state (state BEFORE consuming word s)
        float hp = hsh[b][j];
        hcat[(s * B + b) * 32 + dir * HID + j] = (__bf16)hp;
        // h_new = tanh(W . [x, h] + b)
        float acc = bsh[j], acc2 = 0.f;
        #pragma unroll
        for (int e = 0; e < EMB; e += 2) {
            acc  += Wsh[j][e]     * embsh[b][e];
            acc2 += Wsh[j][e + 1] * embsh[b][e + 1];
        }
        #pragma unroll
        for (int k = 0; k < HID; k += 2) {
            acc  += Wsh[j][EMB + k]     * hsh[b][k];
            acc2 += Wsh[j][EMB + k + 1] * hsh[b][k + 1];
        }
        float hn = tanhf(acc + acc2);
        __syncthreads();
        hsh[b][j] = hn;
    }
}

// ---------------- K4: pass 1 — per-row sum(exp(logit)) partials -------------------
// grid: (NCHUNK, M/16); block 256 = 4 waves; wave handles every-4th 16x16 tile.
__global__ void k_pass1(const __bf16* __restrict__ hb, const __bf16* __restrict__ Wb,
                        const float* __restrict__ bias, float* __restrict__ partials) {
    const int chunk = blockIdx.x, rt = blockIdx.y;
    const int wave = threadIdx.x >> 6, lane = threadIdx.x & 63;
    const int lr = lane & 15, kg = lane >> 4;
    const int m0 = rt * 16;
    const bf16x8 a = *reinterpret_cast<const bf16x8*>(hb + (m0 + lr) * 32 + kg * 8);
    const f32x4 zero = {0.f, 0.f, 0.f, 0.f};
    float s0 = 0.f, s1 = 0.f, s2 = 0.f, s3 = 0.f;
    const int t0 = chunk * TPC;
    const int t1 = (t0 + TPC < NT) ? (t0 + TPC) : NT;
    for (int tt = t0 + wave; tt < t1; tt += 4) {
        const int v0 = tt * 16;
        bf16x8 bf = *reinterpret_cast<const bf16x8*>(Wb + (v0 + lr) * 32 + kg * 8);
        float bc = bias[v0 + lr];
        f32x4 d = __builtin_amdgcn_mfma_f32_16x16x32_bf16(a, bf, zero, 0, 0, 0);
        s0 += __expf(d[0] + bc);
        s1 += __expf(d[1] + bc);
        s2 += __expf(d[2] + bc);
        s3 += __expf(d[3] + bc);
    }
    // reduce across the 16 lanes sharing kg (cols of this wave's tiles)
    #pragma unroll
    for (int off = 1; off < 16; off <<= 1) {
        s0 += __shfl_xor(s0, off);
        s1 += __shfl_xor(s1, off);
        s2 += __shfl_xor(s2, off);
        s3 += __shfl_xor(s3, off);
    }
    __shared__ float red[4][16];
    if (lr == 0) {
        red[wave][kg * 4 + 0] = s0;
        red[wave][kg * 4 + 1] = s1;
        red[wave][kg * 4 + 2] = s2;
        red[wave][kg * 4 + 3] = s3;
    }
    __syncthreads();
    if (threadIdx.x < 16) {
        float tot = red[0][threadIdx.x] + red[1][threadIdx.x] +
                    red[2][threadIdx.x] + red[3][threadIdx.x];
        partials[(m0 + threadIdx.x) * NCHUNK + chunk] = tot;
    }
}

// ---------------- K5: reduce partials -> logZ per row -----------------------------
__global__ void k_reduce(const float* __restrict__ partials, float* __restrict__ logZ) {
    int r = blockIdx.x * 256 + threadIdx.x;
    if (r >= M) return;
    float tot = 0.f;
    #pragma unroll
    for (int c = 0; c < NCHUNK; ++c) tot += partials[r * NCHUNK + c];
    logZ[r] = logf(tot);
}

// ---------------- K6: pass 2 — recompute logits, write logit - logZ ---------------
// grid: ((NT+3)/4, M/16); block 256 = 4 waves; one 16x16 tile per wave.
__global__ void k_pass2(const __bf16* __restrict__ hb, const __bf16* __restrict__ Wb,
                        const float* __restrict__ bias, const float* __restrict__ logZ,
                        float* __restrict__ out) {
    const int rt = blockIdx.y;
    const int wave = threadIdx.x >> 6, lane = threadIdx.x & 63;
    const int tt = blockIdx.x * 4 + wave;
    if (tt >= NT) return;
    const int lr = lane & 15, kg = lane >> 4;
    const int m0 = rt * 16;
    const bf16x8 a = *reinterpret_cast<const bf16x8*>(hb + (m0 + lr) * 32 + kg * 8);
    const int v0 = tt * 16;
    bf16x8 bf = *reinterpret_cast<const bf16x8*>(Wb + (v0 + lr) * 32 + kg * 8);
    float bc = bias[v0 + lr];
    const f32x4 zero = {0.f, 0.f, 0.f, 0.f};
    f32x4 d = __builtin_amdgcn_mfma_f32_16x16x32_bf16(a, bf, zero, 0, 0, 0);
    const int col = v0 + lr;
    if (col < V) {
        const int rowb = m0 + kg * 4;
        #pragma unroll
        for (int r = 0; r < 4; ++r)
            out[(size_t)(rowb + r) * V + col] = d[r] + bc - logZ[rowb + r];
    }
}

extern "C" void kernel_launch(void* const* d_in, const int* in_sizes, int n_in,
                              void* d_out, int out_size, void* d_ws, size_t ws_size,
                              hipStream_t stream) {
    const int*   idx       = (const int*)d_in[0];
    const float* embedding = (const float*)d_in[1];
    const float* W_lr      = (const float*)d_in[2];
    const float* b_lr      = (const float*)d_in[3];
    const float* W_rl      = (const float*)d_in[4];
    const float* b_rl      = (const float*)d_in[5];
    const float* W_ho      = (const float*)d_in[6];
    const float* b_ho      = (const float*)d_in[7];
    const float* h0        = (const float*)d_in[8];
    float* out = (float*)d_out;

    char* ws = (char*)d_ws;
    size_t off = 0;
    __bf16* Wb      = (__bf16*)(ws + off); off += (size_t)VP * EMB * 2;   // 3,217,408
    float*  bias    = (float*)(ws + off);  off += (size_t)VP * 4;         // 201,088
    __bf16* hb      = (__bf16*)(ws + off); off += (size_t)M * 32 * 2;     // 131,072
    float*  emb_ws  = (float*)(ws + off);  off += (size_t)M * EMB * 4;    // 262,144
    float*  partials= (float*)(ws + off);  off += (size_t)M * NCHUNK * 4; // 65,536
    float*  logZ    = (float*)(ws + off);  off += (size_t)M * 4;          // 8,192
    // total ~3.9 MB of d_ws

    k_gather<<<(M * EMB + 255) / 256, 256, 0, stream>>>(idx, embedding, emb_ws);
    k_prep<<<(VP * EMB + 255) / 256, 256, 0, stream>>>(W_ho, b_ho, Wb, bias);
    k_rnn<<<2, 512, 0, stream>>>(emb_ws, W_lr, b_lr, W_rl, b_rl, h0, hb);
    k_pass1<<<dim3(NCHUNK, M / 16), 256, 0, stream>>>(hb, Wb, bias, partials);
    k_reduce<<<(M + 255) / 256, 256, 0, stream>>>(partials, logZ);
    k_pass2<<<dim3((NT + 3) / 4, M / 16), 256, 0, stream>>>(hb, Wb, bias, logZ, out);
}

// Round 2
// 198.710 us; speedup vs baseline: 1.5157x; 1.5157x over previous
//
#include <hip/hip_runtime.h>
#include <hip/hip_bf16.h>

#define S 64
#define B 32
#define HID 16
#define EMB 32
#define V 50257
#define NT 3142            // ceil(V/16) tiles of 16 cols
#define VP (NT*16)         // 50272 padded V
#define NCHUNK 16
#define TPC 197            // ceil(NT/NCHUNK)
#define M 2048             // S*B rows
#define PREP_BLOCKS 6284   // VP*EMB/256 exactly

using bf16x8 = __attribute__((ext_vector_type(8))) __bf16;
using f32x4  = __attribute__((ext_vector_type(4))) float;

// ---------------- K1: fused prep ---------------------------------------------------
// blocks [0, PREP_BLOCKS): W_ho -> bf16 padded (0), bias padded (-1e30)
// blocks [PREP_BLOCKS, +256): P[dir][m][j] = emb[idx[m]] . Wx_dir[j] + b_dir[j]
__global__ void k_prep(const float* __restrict__ W_ho, const float* __restrict__ b_ho,
                       const int* __restrict__ idx, const float* __restrict__ emb,
                       const float* __restrict__ W_lr, const float* __restrict__ b_lr,
                       const float* __restrict__ W_rl, const float* __restrict__ b_rl,
                       __bf16* __restrict__ Wb, float* __restrict__ bias,
                       float* __restrict__ P) {
    const int bx = blockIdx.x;
    if (bx < PREP_BLOCKS) {
        int i = bx * 256 + threadIdx.x;          // < VP*EMB exactly
        if (i < VP) bias[i] = (i < V) ? b_ho[i] : -1e30f;
        int v = i >> 5;
        Wb[i] = (v < V) ? (__bf16)W_ho[i] : (__bf16)0.f;
    } else {
        int i = (bx - PREP_BLOCKS) * 256 + threadIdx.x;   // 0..65535
        const int dir = i >> 15, r = i & 32767, m = r >> 4, j = r & 15;
        const float* W  = dir ? W_rl : W_lr;
        const float* bb = dir ? b_rl : b_lr;
        const int tok = idx[m];
        const float4* er = reinterpret_cast<const float4*>(emb + (size_t)tok * EMB);
        const float4* wr = reinterpret_cast<const float4*>(W + j * (EMB + HID));
        float acc = bb[j];
        #pragma unroll
        for (int q = 0; q < 8; ++q) {
            float4 e4 = er[q], w4 = wr[q];
            acc += e4.x * w4.x + e4.y * w4.y + e4.z * w4.z + e4.w * w4.w;
        }
        P[i] = acc;
    }
}

// ---------------- K2: serial RNN scans, input-projection hoisted -------------------
// 16 blocks x 64 threads (single wave). block: dir = bx>>3, batch-quad bq = bx&7.
// thread: bl = t>>4 (local batch), j = t&15 (hidden unit).
__global__ void k_rnn(const float* __restrict__ P,
                      const float* __restrict__ W_lr, const float* __restrict__ W_rl,
                      const float* __restrict__ h0, __bf16* __restrict__ hcat) {
    __shared__ float Psh[S * 4 * HID];   // 16 KB: [s][bl][j]
    __shared__ float hsh[4][17];
    const int t = threadIdx.x;
    const int dir = blockIdx.x >> 3, bq = blockIdx.x & 7;
    const int bl = t >> 4, j = t & 15;
    const int b = bq * 4 + bl;
    // stage this block's slice of P: global (dir*2048 + s*32 + b)*16 + j
    {
        const float4* Pg4 = reinterpret_cast<const float4*>(P);
        float4* Ps4 = reinterpret_cast<float4*>(Psh);
        #pragma unroll
        for (int i = 0; i < 16; ++i) {
            int s = (t >> 4) + 4 * i;
            Ps4[t + 64 * i] = Pg4[dir * 8192 + s * 128 + bq * 16 + (t & 15)];
        }
    }
    // Wh (recurrent weights) in registers
    const float* Wd = (dir ? W_rl : W_lr) + j * (EMB + HID) + EMB;
    float wh[16];
    #pragma unroll
    for (int q = 0; q < 4; ++q) {
        float4 w4 = *reinterpret_cast<const float4*>(Wd + q * 4);
        wh[q * 4 + 0] = w4.x; wh[q * 4 + 1] = w4.y;
        wh[q * 4 + 2] = w4.z; wh[q * 4 + 3] = w4.w;
    }
    float hcur = h0[j];
    hsh[bl][j] = hcur;
    __syncthreads();
    for (int step = 0; step < S; ++step) {
        const int s = dir ? (S - 1 - step) : step;
        hcat[(s * B + b) * 32 + dir * HID + j] = (__bf16)hcur;   // pre-state
        float acc = Psh[s * 64 + bl * 16 + j];
        #pragma unroll
        for (int k = 0; k < HID; ++k) acc += wh[k] * hsh[bl][k];
        hcur = tanhf(acc);
        __syncthreads();
        hsh[bl][j] = hcur;
        __syncthreads();
    }
}

// ---------------- K3: pass 1 — per-row sum(exp(logit)) partials --------------------
// grid: (NCHUNK, M/16); block 256 = 4 waves; wave handles every-4th 16x16 tile.
__global__ void k_pass1(const __bf16* __restrict__ hb, const __bf16* __restrict__ Wb,
                        const float* __restrict__ bias, float* __restrict__ partials) {
    const int chunk = blockIdx.x, rt = blockIdx.y;
    const int wave = threadIdx.x >> 6, lane = threadIdx.x & 63;
    const int lr = lane & 15, kg = lane >> 4;
    const int m0 = rt * 16;
    const bf16x8 a = *reinterpret_cast<const bf16x8*>(hb + (m0 + lr) * 32 + kg * 8);
    const f32x4 zero = {0.f, 0.f, 0.f, 0.f};
    float s0 = 0.f, s1 = 0.f, s2 = 0.f, s3 = 0.f;
    const int t0 = chunk * TPC;
    const int t1 = (t0 + TPC < NT) ? (t0 + TPC) : NT;
    for (int tt = t0 + wave; tt < t1; tt += 4) {
        const int v0 = tt * 16;
        bf16x8 bf = *reinterpret_cast<const bf16x8*>(Wb + (v0 + lr) * 32 + kg * 8);
        float bc = bias[v0 + lr];
        f32x4 d = __builtin_amdgcn_mfma_f32_16x16x32_bf16(a, bf, zero, 0, 0, 0);
        s0 += __expf(d[0] + bc);
        s1 += __expf(d[1] + bc);
        s2 += __expf(d[2] + bc);
        s3 += __expf(d[3] + bc);
    }
    #pragma unroll
    for (int off = 1; off < 16; off <<= 1) {
        s0 += __shfl_xor(s0, off);
        s1 += __shfl_xor(s1, off);
        s2 += __shfl_xor(s2, off);
        s3 += __shfl_xor(s3, off);
    }
    __shared__ float red[4][16];
    if (lr == 0) {
        red[wave][kg * 4 + 0] = s0;
        red[wave][kg * 4 + 1] = s1;
        red[wave][kg * 4 + 2] = s2;
        red[wave][kg * 4 + 3] = s3;
    }
    __syncthreads();
    if (threadIdx.x < 16) {
        float tot = red[0][threadIdx.x] + red[1][threadIdx.x] +
                    red[2][threadIdx.x] + red[3][threadIdx.x];
        partials[(m0 + threadIdx.x) * NCHUNK + chunk] = tot;
    }
}

// ---------------- K4: pass 2 — recompute logits, LDS transpose, coalesced write ----
// grid: (ceil(V/256)=197, M/16); block 256 = 4 waves; block covers 16 rows x 256 cols.
__global__ void k_pass2(const __bf16* __restrict__ hb, const __bf16* __restrict__ Wb,
                        const float* __restrict__ bias, const float* __restrict__ partials,
                        float* __restrict__ out) {
    __shared__ float stage[16][260];   // pad 4: kg-stride 1040 % 32 == 16 -> 2-way (free)
    __shared__ float logZsh[16];
    const int t = threadIdx.x;
    const int wave = t >> 6, lane = t & 63;
    const int lr = lane & 15, kg = lane >> 4;
    const int m0 = blockIdx.y * 16;
    const int cb = blockIdx.x * 256;
    if (t < 16) {   // fold the logZ reduction in (overlaps with MFMA below)
        float tot = 0.f;
        #pragma unroll
        for (int c = 0; c < NCHUNK; ++c) tot += partials[(m0 + t) * NCHUNK + c];
        logZsh[t] = logf(tot);
    }
    const bf16x8 a = *reinterpret_cast<const bf16x8*>(hb + (m0 + lr) * 32 + kg * 8);
    const f32x4 zero = {0.f, 0.f, 0.f, 0.f};
    #pragma unroll
    for (int q = 0; q < 4; ++q) {
        const int tt = blockIdx.x * 16 + wave * 4 + q;
        if (tt < NT) {
            const int v0 = tt * 16;
            bf16x8 bf = *reinterpret_cast<const bf16x8*>(Wb + (v0 + lr) * 32 + kg * 8);
            float bc = bias[v0 + lr];
            f32x4 d = __builtin_amdgcn_mfma_f32_16x16x32_bf16(a, bf, zero, 0, 0, 0);
            const int cl = wave * 64 + q * 16 + lr;
            #pragma unroll
            for (int r = 0; r < 4; ++r)
                stage[kg * 4 + r][cl] = d[r] + bc;
        }
    }
    __syncthreads();
    // write phase: wave w owns rows w*4..w*4+3; per row, 4 stores of 64 contiguous floats
    #pragma unroll
    for (int r = 0; r < 4; ++r) {
        const int row = wave * 4 + r;
        const float lz = logZsh[row];
        const size_t R = (size_t)(m0 + row) * V;
        #pragma unroll
        for (int it = 0; it < 4; ++it) {
            const int c = it * 64 + lane;
            const int col = cb + c;
            if (col < V) out[R + col] = stage[row][c] - lz;
        }
    }
}

extern "C" void kernel_launch(void* const* d_in, const int* in_sizes, int n_in,
                              void* d_out, int out_size, void* d_ws, size_t ws_size,
                              hipStream_t stream) {
    const int*   idx       = (const int*)d_in[0];
    const float* embedding = (const float*)d_in[1];
    const float* W_lr      = (const float*)d_in[2];
    const float* b_lr      = (const float*)d_in[3];
    const float* W_rl      = (const float*)d_in[4];
    const float* b_rl      = (const float*)d_in[5];
    const float* W_ho      = (const float*)d_in[6];
    const float* b_ho      = (const float*)d_in[7];
    const float* h0        = (const float*)d_in[8];
    float* out = (float*)d_out;

    char* ws = (char*)d_ws;
    size_t off = 0;
    __bf16* Wb      = (__bf16*)(ws + off); off += (size_t)VP * EMB * 2;     // 3,217,408
    float*  bias    = (float*)(ws + off);  off += (size_t)VP * 4;           //   201,088
    __bf16* hb      = (__bf16*)(ws + off); off += (size_t)M * 32 * 2;       //   131,072
    float*  P       = (float*)(ws + off);  off += (size_t)2 * M * HID * 4;  //   262,144
    float*  partials= (float*)(ws + off);  off += (size_t)M * NCHUNK * 4;   //   131,072
    // total ~3.76 MB of d_ws

    k_prep<<<PREP_BLOCKS + 256, 256, 0, stream>>>(W_ho, b_ho, idx, embedding,
                                                  W_lr, b_lr, W_rl, b_rl, Wb, bias, P);
    k_rnn<<<16, 64, 0, stream>>>(P, W_lr, W_rl, h0, hb);
    k_pass1<<<dim3(NCHUNK, M / 16), 256, 0, stream>>>(hb, Wb, bias, partials);
    k_pass2<<<dim3(197, M / 16), 256, 0, stream>>>(hb, Wb, bias, partials, out);
}